// Round 9
// baseline (405.220 us; speedup 1.0000x reference)
//
#include <hip/hip_runtime.h>
#include <hip/hip_bf16.h>

constexpr int N_NODES = 100000;
constexpr int N_EDGES = 1600000;
constexpr int SCAN_B  = 1024;
constexpr int SCAN_G  = (N_NODES + SCAN_B) / SCAN_B;   // 98 blocks covers N+1 elements
constexpr int FCH     = 8192;                          // edges per chunk (legacy slice kernels)
constexpr int NCH     = (N_EDGES + FCH - 1) / FCH;     // 196
constexpr int SLICE_N = N_NODES / 8;                   // 12500
constexpr int PADC    = 48;                            // padded adjacency capacity/node

// ---- legacy workspace layout (byte offsets), fits 34.9 MB ----
constexpr size_t OFF_FLAG = 0;                 // 2 ints: [0]=fp32 floats, [1]=int32 edges
constexpr size_t OFF_DEG  = 4    * 1024;       // int[N]            (padded path: cnt)
constexpr size_t OFF_DINV = 408  * 1024;       // float[N]
constexpr size_t OFF_OFFS = 812  * 1024;       // int[N+1]          (legacy)
constexpr size_t OFF_CURS = 1216 * 1024;       // int[N]            (legacy)
constexpr size_t OFF_BSUM = 1620 * 1024;       // legacy scan tmp; padded: bucket cursors
constexpr size_t OFF_WC   = 1624 * 1024;       // float[20768] (ends ~1706 KB)
constexpr size_t OFF_CSR  = 1712 * 1024;       // int[E] (6.4 MB)   (legacy)
constexpr size_t OFF_A    = 8192 * 1024;       // bf16 N*64 (12.8 MB)  (legacy)
constexpr size_t OFF_B    = 21504ul * 1024;    // bf16 N*64 (12.8 MB)  (legacy)

// ---- padded-path layout: PAD 1792..20542 KB, A2 20544.., B2 33044.. ----
// During SETUP the A2 region holds the packed bucketed edge buffer (8 MB);
// dead before gemm1 writes A.
constexpr size_t OFF_PAD  = 1792ul  * 1024;    // int[N*PADC] = 18750 KB
constexpr size_t OFF_A2   = 20544ul * 1024;    // bf16 N*64 (12500 KB)
constexpr size_t OFF_B2   = 33044ul * 1024;    // bf16 N*64 (12500 KB)
constexpr size_t NEED_PAD = OFF_B2 + (size_t)N_NODES * 64 * 2;   // ~44.5 MiB
static_assert(OFF_PAD >= OFF_WC + 20768 * 4, "pad must not clobber Wc");
static_assert(OFF_A2 >= OFF_PAD + (size_t)N_NODES * PADC * 4, "A2 overlaps pad");
static_assert(OFF_B2 >= OFF_A2 + (size_t)N_NODES * 64 * 2, "B2 overlaps A2");

// ---- bucketed CSR build (padded path) ----
constexpr int BUK_SH  = 9;                              // 512 nodes per bucket
constexpr int BUK_N   = 512;
constexpr int NBUK    = (N_NODES + BUK_N - 1) / BUK_N;  // 196
constexpr int BUKCAP  = 10240;   // per-bucket edge capacity (mean 8163, sd ~90: +23 sigma)
constexpr int P1_CH   = 4096;
constexpr int P1_BLK  = (N_EDGES + P1_CH - 1) / P1_CH;  // 391
static_assert((size_t)NBUK * BUKCAP * 4 <= (size_t)N_NODES * 64 * 2, "ebuf fits A2");
static_assert(NBUK * 4 <= 4096, "bucket cursors fit BSUM region");
static_assert(NBUK < 255, "bucket id fits uchar with 0xFF sentinel");

// Wc float offsets
constexpr int WC_W1 = 0, WC_W2 = 8192, WC_W3 = 10240, WC_W4 = 12288;
constexpr int WC_B1 = 20480, WC_B2 = 20544, WC_B3 = 20576, WC_B4 = 20640;
constexpr int WC_TOT = 20768;

__device__ __forceinline__ float bf2f(unsigned short b) {
    union { unsigned u; float f; } c; c.u = ((unsigned)b) << 16; return c.f;
}

// f32 -> bf16 bits, round-to-nearest-even
__device__ __forceinline__ short f2bf(float f) {
    union { float f; unsigned u; } c; c.f = f;
    return (short)((c.u + 0x7FFFu + ((c.u >> 16) & 1u)) >> 16);
}

__device__ __forceinline__ int ntload(const int* p) {
    return __builtin_nontemporal_load(p);
}

// ---------------- dtype detection (proven) ----------------
__global__ void detect_kernel(const unsigned* __restrict__ w1raw,
                              const unsigned* __restrict__ eiraw,
                              int* __restrict__ flags) {
    const int t = threadIdx.x;  // 1 block x 256
    int f32 = 0, i32 = 0;
    for (int i = t; i < 1024; i += 256) {
        unsigned lo = w1raw[i] & 0xFFFFu;
        if ((lo & 0x7F80u) >= 0x3F00u) f32 = 1;    // bf16 glorot can't have big low-half exp
    }
    for (int i = t; i < 4096; i += 256)
        if ((i & 1) && eiraw[i] != 0u) i32 = 1;    // int64 high words are all zero
    if (f32) atomicOr(&flags[0], 1);
    if (i32) atomicOr(&flags[1], 1);
}

__device__ __forceinline__ unsigned edge_src(const int* ei, int i64, int e) {
    return (unsigned)(i64 ? ntload(&ei[2 * (size_t)e]) : ntload(&ei[e]));
}
__device__ __forceinline__ unsigned edge_dst(const int* ei, int i64, int e) {
    return (unsigned)(i64 ? ntload(&ei[2 * (size_t)N_EDGES + 2 * (size_t)e])
                          : ntload(&ei[(size_t)N_EDGES + e]));
}

// ---------------- weights -> fp32 ws copies ----------------
__global__ void convw_kernel(const void* W1, const void* b1, const void* W2, const void* b2,
                             const void* W3, const void* b3, const void* W4, const void* b4,
                             const int* __restrict__ flags, float* __restrict__ Wc) {
    int i = blockIdx.x * blockDim.x + threadIdx.x;
    if (i >= WC_TOT) return;
    const void* src; int off;
    if      (i < WC_W2) { src = W1; off = i; }
    else if (i < WC_W3) { src = W2; off = i - WC_W2; }
    else if (i < WC_W4) { src = W3; off = i - WC_W3; }
    else if (i < WC_B1) { src = W4; off = i - WC_W4; }
    else if (i < WC_B2) { src = b1; off = i - WC_B1; }
    else if (i < WC_B3) { src = b2; off = i - WC_B2; }
    else if (i < WC_B4) { src = b3; off = i - WC_B3; }
    else                { src = b4; off = i - WC_B4; }
    Wc[i] = flags[0] ? ((const float*)src)[off]
                     : __bfloat162float(((const __hip_bfloat16*)src)[off]);
}

// ---------------- bucketed build, phase 1: bucket the edges ----------------
// LDS-staged: one read of the edge list (r8's version re-read ei for the write
// pass: +25.6 MB fetch). Edges packed to one int: (dloc<<17)|src (26 bits).
// ONE global atomic per nonzero (block,bucket) to reserve ranges (~76K total).
__global__ __launch_bounds__(256) void bsort1_kernel(
        const int* __restrict__ ei, const int* __restrict__ flags,
        int* __restrict__ gcur, int* __restrict__ ebuf) {
    __shared__ int hist[NBUK], rbase[NBUK], cur[NBUK];
    __shared__ int pk[P1_CH];
    __shared__ unsigned char bk[P1_CH];
    const int i64 = (flags[1] == 0);
    for (int i = threadIdx.x; i < NBUK; i += 256) { hist[i] = 0; cur[i] = 0; }
    __syncthreads();
    const int e0 = blockIdx.x * P1_CH;
    const int ne = min(P1_CH, N_EDGES - e0);
    for (int i = threadIdx.x; i < ne; i += 256) {
        const unsigned d = edge_dst(ei, i64, e0 + i);
        const unsigned s = edge_src(ei, i64, e0 + i);
        if (d < (unsigned)N_NODES && s < (unsigned)N_NODES) {
            const int b = (int)(d >> BUK_SH);
            atomicAdd(&hist[b], 1);
            bk[i] = (unsigned char)b;
            pk[i] = (int)(((d & (BUK_N - 1)) << 17) | s);
        } else {
            bk[i] = 0xFF;
        }
    }
    __syncthreads();
    for (int b = threadIdx.x; b < NBUK; b += 256)
        rbase[b] = hist[b] ? atomicAdd(&gcur[b], hist[b]) : 0;
    __syncthreads();
    for (int i = threadIdx.x; i < ne; i += 256) {
        const int b = bk[i];
        if (b != 0xFF) {
            const int p = rbase[b] + atomicAdd(&cur[b], 1);
            if (p < BUKCAP) ebuf[(size_t)b * BUKCAP + p] = pk[i];
        }
    }
}

// ---------------- bucketed build, phase 2: LDS-cursor pad fill ----------------
// One 1024-thread block per bucket (512 nodes). Per-edge atomics are LDS-only.
// cnt + dinv written densely here.
__global__ __launch_bounds__(1024) void bsort2_kernel(
        const int* __restrict__ gcur, const int* __restrict__ ebuf,
        int* __restrict__ cnt, int* __restrict__ pad, float* __restrict__ dinv) {
    __shared__ int lc[BUK_N];
    const int b  = blockIdx.x;
    const int n0 = b * BUK_N;
    const int nn = min(BUK_N, N_NODES - n0);
    if (threadIdx.x < BUK_N) lc[threadIdx.x] = 0;
    __syncthreads();
    const int ne = min(gcur[b], BUKCAP);
    for (int i = threadIdx.x; i < ne; i += 1024) {
        const int v = ebuf[(size_t)b * BUKCAP + i];
        const int dloc = v >> 17;
        const int s = v & 0x1FFFF;
        const int pos = atomicAdd(&lc[dloc], 1);
        if (pos < PADC) pad[(size_t)(n0 + dloc) * PADC + pos] = s;
    }
    __syncthreads();
    for (int t = threadIdx.x; t < nn; t += 1024) {
        const int c = lc[t];
        cnt[n0 + t]  = c;
        dinv[n0 + t] = rsqrtf((float)c + 1.0f);
    }
}

// ---------------- legacy: slice-local degree histogram ----------------
__global__ void deg_kernel(const int* __restrict__ ei, const int* __restrict__ flags,
                           int* __restrict__ deg) {
    const int slice = blockIdx.x & 7;
    const int chunk = blockIdx.x >> 3;
    const int i64 = (flags[1] == 0);
    const unsigned lo = (unsigned)(slice * SLICE_N);
    const int e0 = chunk * FCH;
    const int e1 = min(e0 + FCH, N_EDGES);
    for (int e = e0 + threadIdx.x; e < e1; e += 256) {
        unsigned d = edge_dst(ei, i64, e);
        if (d - lo < (unsigned)SLICE_N && d < (unsigned)N_NODES) atomicAdd(&deg[d], 1);
    }
}

__global__ void dinv_kernel(const int* __restrict__ deg, float* __restrict__ dinv) {
    int n = blockIdx.x * blockDim.x + threadIdx.x;
    if (n < N_NODES) dinv[n] = rsqrtf((float)deg[n] + 1.0f);
}

// ---------------- legacy: hierarchical exclusive scan of deg -> offsets ----------------
__global__ __launch_bounds__(1024) void scan1_kernel(const int* __restrict__ deg,
                                                     int* __restrict__ bsum) {
    const int i = blockIdx.x * SCAN_B + threadIdx.x;
    const int lane = threadIdx.x & 63, wid = threadIdx.x >> 6;
    int v = (i < N_NODES) ? deg[i] : 0;
    for (int o = 32; o > 0; o >>= 1) v += __shfl_down(v, o, 64);
    __shared__ int ws[16];
    if (lane == 0) ws[wid] = v;
    __syncthreads();
    if (wid == 0) {
        int t = (lane < 16) ? ws[lane] : 0;
        for (int o = 8; o > 0; o >>= 1) t += __shfl_down(t, o, 64);
        if (lane == 0) bsum[blockIdx.x] = t;
    }
}

__global__ void scan2_kernel(const int* __restrict__ bsum, int* __restrict__ boff) {
    const int t = threadIdx.x;   // 1 block x 128
    __shared__ int tmp[128];
    int v = (t < SCAN_G) ? bsum[t] : 0;
    tmp[t] = v;
    __syncthreads();
    for (int o = 1; o < 128; o <<= 1) {
        int a = (t >= o) ? tmp[t - o] : 0;
        __syncthreads();
        tmp[t] += a;
        __syncthreads();
    }
    boff[t] = tmp[t] - v;        // exclusive
}

__global__ __launch_bounds__(1024) void scan3_kernel(const int* __restrict__ deg,
                                                     const int* __restrict__ boff,
                                                     int* __restrict__ offs,
                                                     int* __restrict__ curs) {
    const int i = blockIdx.x * SCAN_B + threadIdx.x;
    const int lane = threadIdx.x & 63, wid = threadIdx.x >> 6;
    int v = (i < N_NODES) ? deg[i] : 0;
    int incl = v;
    for (int o = 1; o < 64; o <<= 1) {
        int t = __shfl_up(incl, (unsigned)o, 64);
        if (lane >= o) incl += t;
    }
    __shared__ int wsum[16], woff[16];
    if (lane == 63) wsum[wid] = incl;
    __syncthreads();
    if (wid == 0 && lane < 16) {
        int u = wsum[lane];
        int uin = u;
        for (int o = 1; o < 16; o <<= 1) {
            int t = __shfl_up(uin, (unsigned)o, 64);
            if (lane >= o) uin += t;
        }
        woff[lane] = uin - u;
    }
    __syncthreads();
    const int excl = incl - v + woff[wid] + boff[blockIdx.x];
    if (i <= N_NODES) {
        offs[i] = excl;
        if (i < N_NODES) curs[i] = excl;
    }
}

// ---------------- legacy: slice-local CSR fill ----------------
__global__ void fill_kernel(const int* __restrict__ ei, const int* __restrict__ flags,
                            int* __restrict__ curs, int* __restrict__ csr) {
    const int slice = blockIdx.x & 7;
    const int chunk = blockIdx.x >> 3;
    const int i64 = (flags[1] == 0);
    const unsigned lo = (unsigned)(slice * SLICE_N);
    const int e0 = chunk * FCH;
    const int e1 = min(e0 + FCH, N_EDGES);
    for (int e = e0 + threadIdx.x; e < e1; e += 256) {
        unsigned d = edge_dst(ei, i64, e);
        if (d - lo < (unsigned)SLICE_N && d < (unsigned)N_NODES) {
            unsigned s = edge_src(ei, i64, e);
            if (s < (unsigned)N_NODES) {
                int pos = atomicAdd(&curs[d], 1);
                if ((unsigned)pos < (unsigned)N_EDGES) csr[pos] = (int)s;
            }
        }
    }
}

// ---------------- MFMA GEMM: out = epi(in @ Wc + bias) [*dinv] ----------------
// One wave owns a 16-row node stripe x full OUT. N_NODES % 16 == 0 -> no bounds checks.
// C/D layout (m89-verified): col = lane&15, row = (lane>>4)*4 + reg.
typedef __attribute__((ext_vector_type(8))) short bf16x8;
typedef __attribute__((ext_vector_type(4))) float f32x4;

constexpr int NTILES    = N_NODES / 16;   // 6250
constexpr int GEMM_GRID = 512;
static_assert(N_NODES % 16 == 0, "tile grid requires multiple of 16");

template <int IN, int OUT, bool DYNIN, bool RELU, bool BIAS, bool SCALE, bool HASWS, bool HASG>
__global__ __launch_bounds__(256) void gemm_mfma(
        const void* __restrict__ in, int inLD, const int* __restrict__ flags,
        const float* __restrict__ Wc, int WLD, const float* __restrict__ bias,
        const float* __restrict__ dinv,
        __hip_bfloat16* __restrict__ wsout,            // bf16 ws, or unused
        void* __restrict__ gout, int gLD) {            // dtype-branch global, or unused
    constexpr int KS = IN / 32;    // k-steps
    constexpr int NT = OUT / 16;   // column tiles
    static_assert(IN % 32 == 0 && OUT % 16 == 0, "shape");
    const int lane = threadIdx.x & 63;
    const int wid  = threadIdx.x >> 6;
    const int m = lane & 15;       // A-row / B-col / D-col within tile
    const int g = lane >> 4;       // k-group
    const int f32f = flags[0];

    bf16x8 bfrag[NT][KS];
#pragma unroll
    for (int t = 0; t < NT; ++t) {
#pragma unroll
        for (int ks = 0; ks < KS; ++ks) {
            const float* wp = Wc + (size_t)(ks * 32 + g * 8) * WLD + t * 16 + m;
            bf16x8 b;
#pragma unroll
            for (int j = 0; j < 8; ++j) b[j] = f2bf(wp[(size_t)j * WLD]);
            bfrag[t][ks] = b;
        }
    }
    float bb[NT];
    if (BIAS) {
#pragma unroll
        for (int t = 0; t < NT; ++t) bb[t] = bias[t * 16 + m];
    }

    for (int tile = blockIdx.x * 4 + wid; tile < NTILES; tile += GEMM_GRID * 4) {
        f32x4 acc[NT];
#pragma unroll
        for (int t = 0; t < NT; ++t) {
            const float b0 = BIAS ? bb[t] : 0.0f;
            acc[t] = (f32x4){b0, b0, b0, b0};
        }
        const size_t arow = (size_t)tile * 16 + m;
#pragma unroll
        for (int ks = 0; ks < KS; ++ks) {
            bf16x8 af;
            if (DYNIN && f32f) {
                const float* xp = (const float*)in + arow * inLD + ks * 32 + g * 8;
                const float4 v0 = *(const float4*)xp;
                const float4 v1 = *(const float4*)(xp + 4);
                af[0] = f2bf(v0.x); af[1] = f2bf(v0.y);
                af[2] = f2bf(v0.z); af[3] = f2bf(v0.w);
                af[4] = f2bf(v1.x); af[5] = f2bf(v1.y);
                af[6] = f2bf(v1.z); af[7] = f2bf(v1.w);
            } else {
                af = *(const bf16x8*)((const __hip_bfloat16*)in + arow * inLD + ks * 32 + g * 8);
            }
#pragma unroll
            for (int t = 0; t < NT; ++t)
                acc[t] = __builtin_amdgcn_mfma_f32_16x16x32_bf16(af, bfrag[t][ks], acc[t], 0, 0, 0);
        }
        const int rbase = tile * 16 + g * 4;
        float di[4];
        if (SCALE) {
#pragma unroll
            for (int r = 0; r < 4; ++r) di[r] = dinv[rbase + r];
        }
#pragma unroll
        for (int t = 0; t < NT; ++t) {
            const int col = t * 16 + m;
#pragma unroll
            for (int r = 0; r < 4; ++r) {
                float v = acc[t][r];
                if (RELU) v = fmaxf(v, 0.0f);
                if (SCALE) v *= di[r];
                const size_t row = (size_t)(rbase + r);
                if (HASWS) wsout[row * OUT + col] = __float2bfloat16(v);
                if (HASG) {
                    const size_t gi = row * gLD + col;
                    if (f32f) ((float*)gout)[gi] = v;
                    else      ((__hip_bfloat16*)gout)[gi] = __float2bfloat16(v);
                }
            }
        }
    }
}

// ---------------- aggregation over padded adjacency (PADDED) or CSR ----------------
template <int D, int SUBW, bool RELU, bool PADDED>
__global__ __launch_bounds__(256) void agg_kernel(
        const int* __restrict__ base, const int* __restrict__ adj,
        const float* __restrict__ dinv,
        const __hip_bfloat16* __restrict__ h,     // N x D, dinv-prescaled
        const float* __restrict__ bias,           // null -> 0
        __hip_bfloat16* __restrict__ wsout,       // unscaled bf16, or null
        __hip_bfloat16* __restrict__ wsout_sc,    // *dinv[n] bf16 (prescale next), or null
        void* __restrict__ gout, size_t gbase, int gLD,   // dtype-branch global, or null
        const int* __restrict__ flags) {
    const int lane = threadIdx.x & 63;
    const int wid  = threadIdx.x >> 6;
    constexpr int SPW = 64 / SUBW;                 // subwaves per wave
    constexpr int SPB = 4 * SPW;                   // subwaves per block
    const int n = blockIdx.x * SPB + wid * SPW + (SUBW == 64 ? 0 : (lane >> 5));
    if (n >= N_NODES) return;
    const int sl = lane & (SUBW - 1);
    const int col = sl;
    float acc = __bfloat162float(h[(size_t)n * D + col]);   // self-loop term
    int o0, o1;
    if (PADDED) {
        o0 = n * PADC;
        o1 = o0 + min(base[n], PADC);
    } else {
        o0 = base[n]; o1 = base[n + 1];
    }
    for (int bse = o0; bse < o1; bse += SUBW) {
        const int idx = bse + sl;
        const int sid = (idx < o1) ? adj[idx] : 0;
        const int cnt = min(SUBW, o1 - bse);
        int k = 0;
        for (; k + 8 <= cnt; k += 8) {
            int s[8];
#pragma unroll
            for (int u = 0; u < 8; ++u) s[u] = __shfl(sid, k + u, SUBW);
            float v[8];
#pragma unroll
            for (int u = 0; u < 8; ++u) v[u] = __bfloat162float(h[(size_t)s[u] * D + col]);
            acc += ((v[0] + v[1]) + (v[2] + v[3])) + ((v[4] + v[5]) + (v[6] + v[7]));
        }
        for (; k < cnt; ++k) {
            const int s = __shfl(sid, k, SUBW);
            acc += __bfloat162float(h[(size_t)s * D + col]);
        }
    }
    const float di = dinv[n];
    float v = acc * di;
    if (bias) v += bias[col];
    if (RELU) v = fmaxf(v, 0.0f);
    if (wsout)    wsout[(size_t)n * D + col]    = __float2bfloat16(v);
    if (wsout_sc) wsout_sc[(size_t)n * D + col] = __float2bfloat16(v * di);
    if (gout) {
        const size_t gi = gbase + (size_t)n * gLD + col;
        if (flags[0]) ((float*)gout)[gi] = v;
        else          ((__hip_bfloat16*)gout)[gi] = __float2bfloat16(v);
    }
}

// ---------------- fused agg1+gemm2 (padded path) ----------------
// out32[n] = ( relu( dinv[n]*(Σ h[s] + h[n]) + b1 ) @ W2 ) * dinv[n], bf16
// h = A (N x 64, prescaled). One node per wave (SUBW=64). N % 4 == 0 -> exact grid.
__global__ __launch_bounds__(256) void aggmm1_kernel(
        const int* __restrict__ cnt, const int* __restrict__ pad,
        const float* __restrict__ dinv,
        const __hip_bfloat16* __restrict__ h,
        const float* __restrict__ W2,      // 64x32 row-major
        const float* __restrict__ b1,
        __hip_bfloat16* __restrict__ out32) {
    __shared__ float Ws[64 * 32];
    __shared__ float Xs[4][64];
    const int tid = threadIdx.x;
    for (int i = tid; i < 64 * 32; i += 256) Ws[i] = W2[i];
    __syncthreads();
    const int lane = tid & 63, wid = tid >> 6;
    const int n = blockIdx.x * 4 + wid;          // grid = N/4 exactly
    float acc = __bfloat162float(h[(size_t)n * 64 + lane]);
    const int o0 = n * PADC;
    const int o1 = o0 + min(cnt[n], PADC);
    for (int bse = o0; bse < o1; bse += 64) {
        const int idx = bse + lane;
        const int sid = (idx < o1) ? pad[idx] : 0;
        const int cn = min(64, o1 - bse);
        int k = 0;
        for (; k + 8 <= cn; k += 8) {
            int s[8];
#pragma unroll
            for (int u = 0; u < 8; ++u) s[u] = __shfl(sid, k + u, 64);
            float v[8];
#pragma unroll
            for (int u = 0; u < 8; ++u) v[u] = __bfloat162float(h[(size_t)s[u] * 64 + lane]);
            acc += ((v[0] + v[1]) + (v[2] + v[3])) + ((v[4] + v[5]) + (v[6] + v[7]));
        }
        for (; k < cn; ++k) {
            const int s = __shfl(sid, k, 64);
            acc += __bfloat162float(h[(size_t)s * 64 + lane]);
        }
    }
    const float di = dinv[n];
    Xs[wid][lane] = fmaxf(acc * di + b1[lane], 0.0f);   // act1; wave-internal RAW, no sync
    const int j = lane & 31;
    float o = 0.0f;
#pragma unroll 8
    for (int k = 0; k < 64; ++k) o = fmaf(Xs[wid][k], Ws[k * 32 + j], o);
    if (lane < 32) out32[(size_t)n * 32 + j] = __float2bfloat16(o * di);
}

// ---------------- fused agg3+gemm3 (padded path) ----------------
// t3[n] = dinv[n]*(Σ h[s] + h[n])  (h = zp, N x 32 prescaled)
// out64[n] = relu( t3 @ W3 + b3 ) * dinv[n], bf16. 2 nodes/wave. N % 8 == 0.
__global__ __launch_bounds__(256) void aggmm3_kernel(
        const int* __restrict__ cnt, const int* __restrict__ pad,
        const float* __restrict__ dinv,
        const __hip_bfloat16* __restrict__ h,
        const float* __restrict__ W3,      // 32x64 row-major
        const float* __restrict__ b3,
        __hip_bfloat16* __restrict__ out64) {
    __shared__ float Ws[32 * 64];
    __shared__ float Xs[8][32];
    const int tid = threadIdx.x;
    for (int i = tid; i < 32 * 64; i += 256) Ws[i] = W3[i];
    __syncthreads();
    const int lane = tid & 63, wid = tid >> 6;
    const int sub = lane >> 5, sl = lane & 31;
    const int sw = wid * 2 + sub;
    const int n = blockIdx.x * 8 + sw;           // grid = N/8 exactly
    float acc = __bfloat162float(h[(size_t)n * 32 + sl]);
    const int o0 = n * PADC;
    const int o1 = o0 + min(cnt[n], PADC);
    for (int bse = o0; bse < o1; bse += 32) {
        const int idx = bse + sl;
        const int sid = (idx < o1) ? pad[idx] : 0;
        const int cn = min(32, o1 - bse);
        int k = 0;
        for (; k + 8 <= cn; k += 8) {
            int s[8];
#pragma unroll
            for (int u = 0; u < 8; ++u) s[u] = __shfl(sid, k + u, 32);
            float v[8];
#pragma unroll
            for (int u = 0; u < 8; ++u) v[u] = __bfloat162float(h[(size_t)s[u] * 32 + sl]);
            acc += ((v[0] + v[1]) + (v[2] + v[3])) + ((v[4] + v[5]) + (v[6] + v[7]));
        }
        for (; k < cn; ++k) {
            const int s = __shfl(sid, k, 32);
            acc += __bfloat162float(h[(size_t)s * 32 + sl]);
        }
    }
    const float di = dinv[n];
    Xs[sw][sl] = acc * di;                       // t3; wave-internal RAW, no sync
    float p0 = 0.0f, p1 = 0.0f;
#pragma unroll 8
    for (int k = 0; k < 32; ++k) {
        const float a = Xs[sw][k];
        p0 = fmaf(a, Ws[k * 64 + sl], p0);
        p1 = fmaf(a, Ws[k * 64 + sl + 32], p1);
    }
    p0 = fmaxf(p0 + b3[sl], 0.0f) * di;
    p1 = fmaxf(p1 + b3[sl + 32], 0.0f) * di;
    out64[(size_t)n * 64 + sl]      = __float2bfloat16(p0);
    out64[(size_t)n * 64 + sl + 32] = __float2bfloat16(p1);
}

// ---------------- legacy 4-layer pipeline ----------------
template <bool P>
static inline void run_layers(const void* x, const int* flags, float* Wc, float* dinv,
                              const int* base, const int* adj,
                              __hip_bfloat16* A, __hip_bfloat16* B,
                              void* d_out, hipStream_t stream) {
    gemm_mfma<128, 64, true, false, false, true, true, false><<<GEMM_GRID, 256, 0, stream>>>(
        x, 128, flags, Wc + WC_W1, 64, nullptr, dinv, A, nullptr, 0);
    agg_kernel<64, 64, true, P><<<(N_NODES + 3) / 4, 256, 0, stream>>>(
        base, adj, dinv, A, Wc + WC_B1, B, nullptr, nullptr, 0, 0, flags);
    gemm_mfma<64, 32, false, false, false, true, true, false><<<GEMM_GRID, 256, 0, stream>>>(
        B, 64, flags, Wc + WC_W2, 32, nullptr, dinv, A, nullptr, 0);
    agg_kernel<32, 32, false, P><<<(N_NODES + 7) / 8, 256, 0, stream>>>(
        base, adj, dinv, A, Wc + WC_B2, nullptr, B,
        d_out, (size_t)N_NODES * 128, 32, flags);
    agg_kernel<32, 32, false, P><<<(N_NODES + 7) / 8, 256, 0, stream>>>(
        base, adj, dinv, B, nullptr, A, nullptr, nullptr, 0, 0, flags);
    gemm_mfma<32, 64, false, true, true, true, true, false><<<GEMM_GRID, 256, 0, stream>>>(
        A, 32, flags, Wc + WC_W3, 64, Wc + WC_B3, dinv, B, nullptr, 0);
    agg_kernel<64, 64, false, P><<<(N_NODES + 3) / 4, 256, 0, stream>>>(
        base, adj, dinv, B, nullptr, A, nullptr, nullptr, 0, 0, flags);
    gemm_mfma<64, 128, false, false, true, false, false, true><<<GEMM_GRID, 256, 0, stream>>>(
        A, 64, flags, Wc + WC_W4, 128, Wc + WC_B4, dinv, nullptr, d_out, 128);
}

// ---------------- launch ----------------
extern "C" void kernel_launch(void* const* d_in, const int* in_sizes, int n_in,
                              void* d_out, int out_size, void* d_ws, size_t ws_size,
                              hipStream_t stream) {
    const void* x  = d_in[0];
    const int* ei  = (const int*)d_in[1];
    const void* W1 = d_in[2]; const void* b1 = d_in[3];
    const void* W2 = d_in[4]; const void* b2 = d_in[5];
    const void* W3 = d_in[6]; const void* b3 = d_in[7];
    const void* W4 = d_in[8]; const void* b4 = d_in[9];

    char* ws = (char*)d_ws;
    int*   flags = (int*)(ws + OFF_FLAG);
    int*   cnt   = (int*)(ws + OFF_DEG);     // padded: degree/count; legacy: deg
    float* dinv  = (float*)(ws + OFF_DINV);
    float* Wc    = (float*)(ws + OFF_WC);

    hipMemsetAsync(flags, 0, 2 * sizeof(int), stream);
    hipMemsetAsync(cnt, 0, (size_t)N_NODES * sizeof(int), stream);
    detect_kernel<<<1, 256, 0, stream>>>((const unsigned*)W1, (const unsigned*)ei, flags);
    convw_kernel<<<(WC_TOT + 255) / 256, 256, 0, stream>>>(W1, b1, W2, b2, W3, b3, W4, b4,
                                                           flags, Wc);

    if (ws_size >= NEED_PAD) {
        // ---- bucketed padded adjacency build (no per-edge global atomics) ----
        int*  pad  = (int*)(ws + OFF_PAD);
        int*  gcur = (int*)(ws + OFF_BSUM);                 // NBUK ints (legacy-only region)
        int*  ebuf = (int*)(ws + OFF_A2);                   // 8 MB, dead before gemm1
        __hip_bfloat16* A   = (__hip_bfloat16*)(ws + OFF_A2);   // N x 64
        __hip_bfloat16* C32 = (__hip_bfloat16*)(ws + OFF_B2);   // N x 32 (h2'-prescaled)
        __hip_bfloat16* D32 = C32 + (size_t)N_NODES * 32;       // N x 32 (zp)
        __hip_bfloat16* B   = (__hip_bfloat16*)(ws + OFF_B2);   // N x 64 (t4; after D32 dead)
        hipMemsetAsync(gcur, 0, NBUK * sizeof(int), stream);
        bsort1_kernel<<<P1_BLK, 256, 0, stream>>>(ei, flags, gcur, ebuf);
        bsort2_kernel<<<NBUK, 1024, 0, stream>>>(gcur, ebuf, cnt, pad, dinv);

        // L1 gemm: A = (x@W1)*dinv
        gemm_mfma<128, 64, true, false, false, true, true, false><<<GEMM_GRID, 256, 0, stream>>>(
            x, 128, flags, Wc + WC_W1, 64, nullptr, dinv, A, nullptr, 0);
        // L1 agg + L2 gemm fused: C32 = (relu(agg(A)+b1)@W2)*dinv
        aggmm1_kernel<<<N_NODES / 4, 256, 0, stream>>>(
            cnt, pad, dinv, A, Wc + WC_W2, Wc + WC_B1, C32);
        // L2 agg: z -> d_out, zp -> D32
        agg_kernel<32, 32, false, true><<<(N_NODES + 7) / 8, 256, 0, stream>>>(
            cnt, pad, dinv, C32, Wc + WC_B2, nullptr, D32,
            d_out, (size_t)N_NODES * 128, 32, flags);
        // L3 agg + gemm fused: A = relu(agg(D32)@W3+b3)*dinv  (act3p-prescaled)
        aggmm3_kernel<<<N_NODES / 8, 256, 0, stream>>>(
            cnt, pad, dinv, D32, Wc + WC_W3, Wc + WC_B3, A);
        // L4 agg: B = t4 (unscaled)
        agg_kernel<64, 64, false, true><<<(N_NODES + 3) / 4, 256, 0, stream>>>(
            cnt, pad, dinv, A, nullptr, B, nullptr, nullptr, 0, 0, flags);
        // L4 gemm: d_out = t4@W4 + b4
        gemm_mfma<64, 128, false, false, true, false, false, true><<<GEMM_GRID, 256, 0, stream>>>(
            B, 64, flags, Wc + WC_W4, 128, Wc + WC_B4, dinv, nullptr, d_out, 128);
    } else {
        // ---- legacy exact-CSR path ----
        int*   offs  = (int*)(ws + OFF_OFFS);
        int*   curs  = (int*)(ws + OFF_CURS);
        int*   bsum  = (int*)(ws + OFF_BSUM);
        int*   boff  = bsum + 128;
        int*   csr   = (int*)(ws + OFF_CSR);
        __hip_bfloat16* A = (__hip_bfloat16*)(ws + OFF_A);
        __hip_bfloat16* B = (__hip_bfloat16*)(ws + OFF_B);
        deg_kernel<<<8 * NCH, 256, 0, stream>>>(ei, flags, cnt);
        dinv_kernel<<<(N_NODES + 255) / 256, 256, 0, stream>>>(cnt, dinv);
        scan1_kernel<<<SCAN_G, SCAN_B, 0, stream>>>(cnt, bsum);
        scan2_kernel<<<1, 128, 0, stream>>>(bsum, boff);
        scan3_kernel<<<SCAN_G, SCAN_B, 0, stream>>>(cnt, boff, offs, curs);
        fill_kernel<<<8 * NCH, 256, 0, stream>>>(ei, flags, curs, csr);
        run_layers<false>(x, flags, Wc, dinv, offs, csr, A, B, d_out, stream);
    }
}

// Round 10
// 339.938 us; speedup vs baseline: 1.1920x; 1.1920x over previous
//
#include <hip/hip_runtime.h>
#include <hip/hip_bf16.h>

constexpr int N_NODES = 100000;
constexpr int N_EDGES = 1600000;
constexpr int SCAN_B  = 1024;
constexpr int SCAN_G  = (N_NODES + SCAN_B) / SCAN_B;   // 98 blocks covers N+1 elements
constexpr int FCH     = 8192;                          // edges per chunk (legacy slice kernels)
constexpr int NCH     = (N_EDGES + FCH - 1) / FCH;     // 196
constexpr int SLICE_N = N_NODES / 8;                   // 12500
constexpr int PADC    = 48;                            // padded adjacency capacity/node

// ---- legacy workspace layout (byte offsets), fits 34.9 MB ----
constexpr size_t OFF_FLAG = 0;                 // 2 ints: [0]=fp32 floats, [1]=int32 edges
constexpr size_t OFF_DEG  = 4    * 1024;       // int[N]            (padded path: cnt)
constexpr size_t OFF_DINV = 408  * 1024;       // float[N]
constexpr size_t OFF_OFFS = 812  * 1024;       // int[N+1]          (legacy)
constexpr size_t OFF_CURS = 1216 * 1024;       // int[N]            (legacy)
constexpr size_t OFF_BSUM = 1620 * 1024;       // legacy scan tmp; padded: bucket cursors
constexpr size_t OFF_WC   = 1624 * 1024;       // float[20768] (ends ~1706 KB)
constexpr size_t OFF_CSR  = 1712 * 1024;       // int[E] (6.4 MB)   (legacy)
constexpr size_t OFF_A    = 8192 * 1024;       // bf16 N*64 (12.8 MB)  (legacy)
constexpr size_t OFF_B    = 21504ul * 1024;    // bf16 N*64 (12.8 MB)  (legacy)

// ---- padded-path layout: PAD 1792..20542 KB, A2 20544.., B2 33044.. ----
// During SETUP the A2 region holds the packed bucketed edge buffer (8 MB);
// dead before gemm1 writes A.
constexpr size_t OFF_PAD  = 1792ul  * 1024;    // int[N*PADC] = 18750 KB
constexpr size_t OFF_A2   = 20544ul * 1024;    // bf16 N*64 (12500 KB)
constexpr size_t OFF_B2   = 33044ul * 1024;    // bf16 N*64 (12500 KB)
constexpr size_t NEED_PAD = OFF_B2 + (size_t)N_NODES * 64 * 2;   // ~44.5 MiB
static_assert(OFF_PAD >= OFF_WC + 20768 * 4, "pad must not clobber Wc");
static_assert(OFF_A2 >= OFF_PAD + (size_t)N_NODES * PADC * 4, "A2 overlaps pad");
static_assert(OFF_B2 >= OFF_A2 + (size_t)N_NODES * 64 * 2, "B2 overlaps A2");

// ---- bucketed CSR build (padded path) ----
constexpr int BUK_SH  = 9;                              // 512 nodes per bucket
constexpr int BUK_N   = 512;
constexpr int NBUK    = (N_NODES + BUK_N - 1) / BUK_N;  // 196
constexpr int BUKCAP  = 10240;   // per-bucket edge capacity (mean 8163, sd ~90: +23 sigma)
constexpr int P1_CH   = 4096;
constexpr int P1_BLK  = (N_EDGES + P1_CH - 1) / P1_CH;  // 391
static_assert((size_t)NBUK * BUKCAP * 4 <= (size_t)N_NODES * 64 * 2, "ebuf fits A2");
static_assert(NBUK * 4 <= 4096, "bucket cursors fit BSUM region");
static_assert(NBUK < 255, "bucket id fits uchar with 0xFF sentinel");

// Wc float offsets
constexpr int WC_W1 = 0, WC_W2 = 8192, WC_W3 = 10240, WC_W4 = 12288;
constexpr int WC_B1 = 20480, WC_B2 = 20544, WC_B3 = 20576, WC_B4 = 20640;
constexpr int WC_TOT = 20768;

__device__ __forceinline__ float bf2f(unsigned short b) {
    union { unsigned u; float f; } c; c.u = ((unsigned)b) << 16; return c.f;
}

// f32 -> bf16 bits, round-to-nearest-even
__device__ __forceinline__ short f2bf(float f) {
    union { float f; unsigned u; } c; c.f = f;
    return (short)((c.u + 0x7FFFu + ((c.u >> 16) & 1u)) >> 16);
}

__device__ __forceinline__ int ntload(const int* p) {
    return __builtin_nontemporal_load(p);
}

// ---------------- dtype detection (proven) ----------------
__global__ void detect_kernel(const unsigned* __restrict__ w1raw,
                              const unsigned* __restrict__ eiraw,
                              int* __restrict__ flags) {
    const int t = threadIdx.x;  // 1 block x 256
    int f32 = 0, i32 = 0;
    for (int i = t; i < 1024; i += 256) {
        unsigned lo = w1raw[i] & 0xFFFFu;
        if ((lo & 0x7F80u) >= 0x3F00u) f32 = 1;    // bf16 glorot can't have big low-half exp
    }
    for (int i = t; i < 4096; i += 256)
        if ((i & 1) && eiraw[i] != 0u) i32 = 1;    // int64 high words are all zero
    if (f32) atomicOr(&flags[0], 1);
    if (i32) atomicOr(&flags[1], 1);
}

__device__ __forceinline__ unsigned edge_src(const int* ei, int i64, int e) {
    return (unsigned)(i64 ? ntload(&ei[2 * (size_t)e]) : ntload(&ei[e]));
}
__device__ __forceinline__ unsigned edge_dst(const int* ei, int i64, int e) {
    return (unsigned)(i64 ? ntload(&ei[2 * (size_t)N_EDGES + 2 * (size_t)e])
                          : ntload(&ei[(size_t)N_EDGES + e]));
}

// ---------------- weights -> fp32 ws copies ----------------
__global__ void convw_kernel(const void* W1, const void* b1, const void* W2, const void* b2,
                             const void* W3, const void* b3, const void* W4, const void* b4,
                             const int* __restrict__ flags, float* __restrict__ Wc) {
    int i = blockIdx.x * blockDim.x + threadIdx.x;
    if (i >= WC_TOT) return;
    const void* src; int off;
    if      (i < WC_W2) { src = W1; off = i; }
    else if (i < WC_W3) { src = W2; off = i - WC_W2; }
    else if (i < WC_W4) { src = W3; off = i - WC_W3; }
    else if (i < WC_B1) { src = W4; off = i - WC_W4; }
    else if (i < WC_B2) { src = b1; off = i - WC_B1; }
    else if (i < WC_B3) { src = b2; off = i - WC_B2; }
    else if (i < WC_B4) { src = b3; off = i - WC_B3; }
    else                { src = b4; off = i - WC_B4; }
    Wc[i] = flags[0] ? ((const float*)src)[off]
                     : __bfloat162float(((const __hip_bfloat16*)src)[off]);
}

// ---------------- bucketed build, phase 1: bucket the edges ----------------
// LDS-staged: one read of the edge list. Edges packed to one int: (dloc<<17)|src.
// ONE global atomic per nonzero (block,bucket) to reserve ranges (~76K total vs
// 1.6M per-edge — r4/r6/r7: per-edge device atomics cost ~100 MB EA write traffic).
__global__ __launch_bounds__(256) void bsort1_kernel(
        const int* __restrict__ ei, const int* __restrict__ flags,
        int* __restrict__ gcur, int* __restrict__ ebuf) {
    __shared__ int hist[NBUK], rbase[NBUK], cur[NBUK];
    __shared__ int pk[P1_CH];
    __shared__ unsigned char bk[P1_CH];
    const int i64 = (flags[1] == 0);
    for (int i = threadIdx.x; i < NBUK; i += 256) { hist[i] = 0; cur[i] = 0; }
    __syncthreads();
    const int e0 = blockIdx.x * P1_CH;
    const int ne = min(P1_CH, N_EDGES - e0);
    for (int i = threadIdx.x; i < ne; i += 256) {
        const unsigned d = edge_dst(ei, i64, e0 + i);
        const unsigned s = edge_src(ei, i64, e0 + i);
        if (d < (unsigned)N_NODES && s < (unsigned)N_NODES) {
            const int b = (int)(d >> BUK_SH);
            atomicAdd(&hist[b], 1);
            bk[i] = (unsigned char)b;
            pk[i] = (int)(((d & (BUK_N - 1)) << 17) | s);
        } else {
            bk[i] = 0xFF;
        }
    }
    __syncthreads();
    for (int b = threadIdx.x; b < NBUK; b += 256)
        rbase[b] = hist[b] ? atomicAdd(&gcur[b], hist[b]) : 0;
    __syncthreads();
    for (int i = threadIdx.x; i < ne; i += 256) {
        const int b = bk[i];
        if (b != 0xFF) {
            const int p = rbase[b] + atomicAdd(&cur[b], 1);
            if (p < BUKCAP) ebuf[(size_t)b * BUKCAP + p] = pk[i];
        }
    }
}

// ---------------- bucketed build, phase 2: LDS-cursor pad fill ----------------
__global__ __launch_bounds__(1024) void bsort2_kernel(
        const int* __restrict__ gcur, const int* __restrict__ ebuf,
        int* __restrict__ cnt, int* __restrict__ pad, float* __restrict__ dinv) {
    __shared__ int lc[BUK_N];
    const int b  = blockIdx.x;
    const int n0 = b * BUK_N;
    const int nn = min(BUK_N, N_NODES - n0);
    if (threadIdx.x < BUK_N) lc[threadIdx.x] = 0;
    __syncthreads();
    const int ne = min(gcur[b], BUKCAP);
    for (int i = threadIdx.x; i < ne; i += 1024) {
        const int v = ebuf[(size_t)b * BUKCAP + i];
        const int dloc = v >> 17;
        const int s = v & 0x1FFFF;
        const int pos = atomicAdd(&lc[dloc], 1);
        if (pos < PADC) pad[(size_t)(n0 + dloc) * PADC + pos] = s;
    }
    __syncthreads();
    for (int t = threadIdx.x; t < nn; t += 1024) {
        const int c = lc[t];
        cnt[n0 + t]  = c;
        dinv[n0 + t] = rsqrtf((float)c + 1.0f);
    }
}

// ---------------- legacy: slice-local degree histogram ----------------
__global__ void deg_kernel(const int* __restrict__ ei, const int* __restrict__ flags,
                           int* __restrict__ deg) {
    const int slice = blockIdx.x & 7;
    const int chunk = blockIdx.x >> 3;
    const int i64 = (flags[1] == 0);
    const unsigned lo = (unsigned)(slice * SLICE_N);
    const int e0 = chunk * FCH;
    const int e1 = min(e0 + FCH, N_EDGES);
    for (int e = e0 + threadIdx.x; e < e1; e += 256) {
        unsigned d = edge_dst(ei, i64, e);
        if (d - lo < (unsigned)SLICE_N && d < (unsigned)N_NODES) atomicAdd(&deg[d], 1);
    }
}

__global__ void dinv_kernel(const int* __restrict__ deg, float* __restrict__ dinv) {
    int n = blockIdx.x * blockDim.x + threadIdx.x;
    if (n < N_NODES) dinv[n] = rsqrtf((float)deg[n] + 1.0f);
}

// ---------------- legacy: hierarchical exclusive scan of deg -> offsets ----------------
__global__ __launch_bounds__(1024) void scan1_kernel(const int* __restrict__ deg,
                                                     int* __restrict__ bsum) {
    const int i = blockIdx.x * SCAN_B + threadIdx.x;
    const int lane = threadIdx.x & 63, wid = threadIdx.x >> 6;
    int v = (i < N_NODES) ? deg[i] : 0;
    for (int o = 32; o > 0; o >>= 1) v += __shfl_down(v, o, 64);
    __shared__ int ws[16];
    if (lane == 0) ws[wid] = v;
    __syncthreads();
    if (wid == 0) {
        int t = (lane < 16) ? ws[lane] : 0;
        for (int o = 8; o > 0; o >>= 1) t += __shfl_down(t, o, 64);
        if (lane == 0) bsum[blockIdx.x] = t;
    }
}

__global__ void scan2_kernel(const int* __restrict__ bsum, int* __restrict__ boff) {
    const int t = threadIdx.x;   // 1 block x 128
    __shared__ int tmp[128];
    int v = (t < SCAN_G) ? bsum[t] : 0;
    tmp[t] = v;
    __syncthreads();
    for (int o = 1; o < 128; o <<= 1) {
        int a = (t >= o) ? tmp[t - o] : 0;
        __syncthreads();
        tmp[t] += a;
        __syncthreads();
    }
    boff[t] = tmp[t] - v;        // exclusive
}

__global__ __launch_bounds__(1024) void scan3_kernel(const int* __restrict__ deg,
                                                     const int* __restrict__ boff,
                                                     int* __restrict__ offs,
                                                     int* __restrict__ curs) {
    const int i = blockIdx.x * SCAN_B + threadIdx.x;
    const int lane = threadIdx.x & 63, wid = threadIdx.x >> 6;
    int v = (i < N_NODES) ? deg[i] : 0;
    int incl = v;
    for (int o = 1; o < 64; o <<= 1) {
        int t = __shfl_up(incl, (unsigned)o, 64);
        if (lane >= o) incl += t;
    }
    __shared__ int wsum[16], woff[16];
    if (lane == 63) wsum[wid] = incl;
    __syncthreads();
    if (wid == 0 && lane < 16) {
        int u = wsum[lane];
        int uin = u;
        for (int o = 1; o < 16; o <<= 1) {
            int t = __shfl_up(uin, (unsigned)o, 64);
            if (lane >= o) uin += t;
        }
        woff[lane] = uin - u;
    }
    __syncthreads();
    const int excl = incl - v + woff[wid] + boff[blockIdx.x];
    if (i <= N_NODES) {
        offs[i] = excl;
        if (i < N_NODES) curs[i] = excl;
    }
}

// ---------------- legacy: slice-local CSR fill ----------------
__global__ void fill_kernel(const int* __restrict__ ei, const int* __restrict__ flags,
                            int* __restrict__ curs, int* __restrict__ csr) {
    const int slice = blockIdx.x & 7;
    const int chunk = blockIdx.x >> 3;
    const int i64 = (flags[1] == 0);
    const unsigned lo = (unsigned)(slice * SLICE_N);
    const int e0 = chunk * FCH;
    const int e1 = min(e0 + FCH, N_EDGES);
    for (int e = e0 + threadIdx.x; e < e1; e += 256) {
        unsigned d = edge_dst(ei, i64, e);
        if (d - lo < (unsigned)SLICE_N && d < (unsigned)N_NODES) {
            unsigned s = edge_src(ei, i64, e);
            if (s < (unsigned)N_NODES) {
                int pos = atomicAdd(&curs[d], 1);
                if ((unsigned)pos < (unsigned)N_EDGES) csr[pos] = (int)s;
            }
        }
    }
}

// ---------------- MFMA GEMM: out = epi(in @ Wc + bias) [*dinv] ----------------
typedef __attribute__((ext_vector_type(8))) short bf16x8;
typedef __attribute__((ext_vector_type(4))) float f32x4;

constexpr int NTILES    = N_NODES / 16;   // 6250
constexpr int GEMM_GRID = 512;
static_assert(N_NODES % 16 == 0, "tile grid requires multiple of 16");

template <int IN, int OUT, bool DYNIN, bool RELU, bool BIAS, bool SCALE, bool HASWS, bool HASG>
__global__ __launch_bounds__(256) void gemm_mfma(
        const void* __restrict__ in, int inLD, const int* __restrict__ flags,
        const float* __restrict__ Wc, int WLD, const float* __restrict__ bias,
        const float* __restrict__ dinv,
        __hip_bfloat16* __restrict__ wsout,            // bf16 ws, or unused
        void* __restrict__ gout, int gLD) {            // dtype-branch global, or unused
    constexpr int KS = IN / 32;    // k-steps
    constexpr int NT = OUT / 16;   // column tiles
    static_assert(IN % 32 == 0 && OUT % 16 == 0, "shape");
    const int lane = threadIdx.x & 63;
    const int wid  = threadIdx.x >> 6;
    const int m = lane & 15;       // A-row / B-col / D-col within tile
    const int g = lane >> 4;       // k-group
    const int f32f = flags[0];

    bf16x8 bfrag[NT][KS];
#pragma unroll
    for (int t = 0; t < NT; ++t) {
#pragma unroll
        for (int ks = 0; ks < KS; ++ks) {
            const float* wp = Wc + (size_t)(ks * 32 + g * 8) * WLD + t * 16 + m;
            bf16x8 b;
#pragma unroll
            for (int j = 0; j < 8; ++j) b[j] = f2bf(wp[(size_t)j * WLD]);
            bfrag[t][ks] = b;
        }
    }
    float bb[NT];
    if (BIAS) {
#pragma unroll
        for (int t = 0; t < NT; ++t) bb[t] = bias[t * 16 + m];
    }

    for (int tile = blockIdx.x * 4 + wid; tile < NTILES; tile += GEMM_GRID * 4) {
        f32x4 acc[NT];
#pragma unroll
        for (int t = 0; t < NT; ++t) {
            const float b0 = BIAS ? bb[t] : 0.0f;
            acc[t] = (f32x4){b0, b0, b0, b0};
        }
        const size_t arow = (size_t)tile * 16 + m;
#pragma unroll
        for (int ks = 0; ks < KS; ++ks) {
            bf16x8 af;
            if (DYNIN && f32f) {
                const float* xp = (const float*)in + arow * inLD + ks * 32 + g * 8;
                const float4 v0 = *(const float4*)xp;
                const float4 v1 = *(const float4*)(xp + 4);
                af[0] = f2bf(v0.x); af[1] = f2bf(v0.y);
                af[2] = f2bf(v0.z); af[3] = f2bf(v0.w);
                af[4] = f2bf(v1.x); af[5] = f2bf(v1.y);
                af[6] = f2bf(v1.z); af[7] = f2bf(v1.w);
            } else {
                af = *(const bf16x8*)((const __hip_bfloat16*)in + arow * inLD + ks * 32 + g * 8);
            }
#pragma unroll
            for (int t = 0; t < NT; ++t)
                acc[t] = __builtin_amdgcn_mfma_f32_16x16x32_bf16(af, bfrag[t][ks], acc[t], 0, 0, 0);
        }
        const int rbase = tile * 16 + g * 4;
        float di[4];
        if (SCALE) {
#pragma unroll
            for (int r = 0; r < 4; ++r) di[r] = dinv[rbase + r];
        }
#pragma unroll
        for (int t = 0; t < NT; ++t) {
            const int col = t * 16 + m;
#pragma unroll
            for (int r = 0; r < 4; ++r) {
                float v = acc[t][r];
                if (RELU) v = fmaxf(v, 0.0f);
                if (SCALE) v *= di[r];
                const size_t row = (size_t)(rbase + r);
                if (HASWS) wsout[row * OUT + col] = __float2bfloat16(v);
                if (HASG) {
                    const size_t gi = row * gLD + col;
                    if (f32f) ((float*)gout)[gi] = v;
                    else      ((__hip_bfloat16*)gout)[gi] = __float2bfloat16(v);
                }
            }
        }
    }
}

// ---------------- legacy aggregation (scalar loads; CSR path) ----------------
template <int D, int SUBW, bool RELU, bool PADDED>
__global__ __launch_bounds__(256) void agg_kernel(
        const int* __restrict__ base, const int* __restrict__ adj,
        const float* __restrict__ dinv,
        const __hip_bfloat16* __restrict__ h,     // N x D, dinv-prescaled
        const float* __restrict__ bias,           // null -> 0
        __hip_bfloat16* __restrict__ wsout,       // unscaled bf16, or null
        __hip_bfloat16* __restrict__ wsout_sc,    // *dinv[n] bf16 (prescale next), or null
        void* __restrict__ gout, size_t gbase, int gLD,   // dtype-branch global, or null
        const int* __restrict__ flags) {
    const int lane = threadIdx.x & 63;
    const int wid  = threadIdx.x >> 6;
    constexpr int SPW = 64 / SUBW;                 // subwaves per wave
    constexpr int SPB = 4 * SPW;                   // subwaves per block
    const int n = blockIdx.x * SPB + wid * SPW + (SUBW == 64 ? 0 : (lane >> 5));
    if (n >= N_NODES) return;
    const int sl = lane & (SUBW - 1);
    const int col = sl;
    float acc = __bfloat162float(h[(size_t)n * D + col]);   // self-loop term
    int o0, o1;
    if (PADDED) {
        o0 = n * PADC;
        o1 = o0 + min(base[n], PADC);
    } else {
        o0 = base[n]; o1 = base[n + 1];
    }
    for (int bse = o0; bse < o1; bse += SUBW) {
        const int idx = bse + sl;
        const int sid = (idx < o1) ? adj[idx] : 0;
        const int cnt = min(SUBW, o1 - bse);
        int k = 0;
        for (; k + 8 <= cnt; k += 8) {
            int s[8];
#pragma unroll
            for (int u = 0; u < 8; ++u) s[u] = __shfl(sid, k + u, SUBW);
            float v[8];
#pragma unroll
            for (int u = 0; u < 8; ++u) v[u] = __bfloat162float(h[(size_t)s[u] * D + col]);
            acc += ((v[0] + v[1]) + (v[2] + v[3])) + ((v[4] + v[5]) + (v[6] + v[7]));
        }
        for (; k < cnt; ++k) {
            const int s = __shfl(sid, k, SUBW);
            acc += __bfloat162float(h[(size_t)s * D + col]);
        }
    }
    const float di = dinv[n];
    float v = acc * di;
    if (bias) v += bias[col];
    if (RELU) v = fmaxf(v, 0.0f);
    if (wsout)    wsout[(size_t)n * D + col]    = __float2bfloat16(v);
    if (wsout_sc) wsout_sc[(size_t)n * D + col] = __float2bfloat16(v * di);
    if (gout) {
        const size_t gi = gbase + (size_t)n * gLD + col;
        if (flags[0]) ((float*)gout)[gi] = v;
        else          ((__hip_bfloat16*)gout)[gi] = __float2bfloat16(v);
    }
}

// ---------------- vectorized aggregation (padded path) ----------------
// Each lane covers 4 columns (ushort4 = 8 B). A SW=D/4-lane subwave reads a full
// source row per load; one wave processes 64/SW independent nodes concurrently:
// 4x fewer load+shfl instructions and ~4x the outstanding loads vs the scalar agg
// (r8: 8 in flight, VALU 39%, 1.75 TB/s — latency-bound, not BW-bound).
template <int D, bool RELU>
__global__ __launch_bounds__(256) void aggv_kernel(
        const int* __restrict__ cnt, const int* __restrict__ pad,
        const float* __restrict__ dinv,
        const __hip_bfloat16* __restrict__ h,     // N x D, dinv-prescaled
        const float* __restrict__ bias,           // null -> 0
        __hip_bfloat16* __restrict__ wsout,       // unscaled bf16, or null
        __hip_bfloat16* __restrict__ wsout_sc,    // *dinv[n] bf16, or null
        void* __restrict__ gout, size_t gbase, int gLD,   // dtype-branch global, or null
        const int* __restrict__ flags) {
    constexpr int SW  = D / 4;                 // lanes per node (16 for D=64, 8 for D=32)
    constexpr int NPW = 64 / SW;               // nodes per wave
    constexpr int NPB = 4 * NPW;               // nodes per block
    static_assert(N_NODES % NPB == 0, "exact grid");
    const int lane = threadIdx.x & 63;
    const int wid  = threadIdx.x >> 6;
    const int sub  = lane / SW;
    const int sl   = lane % SW;
    const int n = blockIdx.x * NPB + wid * NPW + sub;
    const int col = sl * 4;
    float a0, a1, a2, a3;
    {
        const ushort4 u = *(const ushort4*)&h[(size_t)n * D + col];
        a0 = bf2f(u.x); a1 = bf2f(u.y); a2 = bf2f(u.z); a3 = bf2f(u.w);
    }
    const int o0 = n * PADC;
    const int o1 = o0 + min(cnt[n], PADC);
    for (int bse = o0; bse < o1; bse += SW) {
        const int idx = bse + sl;
        const int sid = (idx < o1) ? pad[idx] : 0;
        const int cn = min(SW, o1 - bse);
        int k = 0;
        for (; k + 8 <= cn; k += 8) {
            int s[8];
#pragma unroll
            for (int u = 0; u < 8; ++u) s[u] = __shfl(sid, k + u, SW);
            ushort4 v[8];
#pragma unroll
            for (int u = 0; u < 8; ++u) v[u] = *(const ushort4*)&h[(size_t)s[u] * D + col];
            a0 += ((bf2f(v[0].x) + bf2f(v[1].x)) + (bf2f(v[2].x) + bf2f(v[3].x))) +
                  ((bf2f(v[4].x) + bf2f(v[5].x)) + (bf2f(v[6].x) + bf2f(v[7].x)));
            a1 += ((bf2f(v[0].y) + bf2f(v[1].y)) + (bf2f(v[2].y) + bf2f(v[3].y))) +
                  ((bf2f(v[4].y) + bf2f(v[5].y)) + (bf2f(v[6].y) + bf2f(v[7].y)));
            a2 += ((bf2f(v[0].z) + bf2f(v[1].z)) + (bf2f(v[2].z) + bf2f(v[3].z))) +
                  ((bf2f(v[4].z) + bf2f(v[5].z)) + (bf2f(v[6].z) + bf2f(v[7].z)));
            a3 += ((bf2f(v[0].w) + bf2f(v[1].w)) + (bf2f(v[2].w) + bf2f(v[3].w))) +
                  ((bf2f(v[4].w) + bf2f(v[5].w)) + (bf2f(v[6].w) + bf2f(v[7].w)));
        }
        for (; k < cn; ++k) {
            const int s = __shfl(sid, k, SW);
            const ushort4 u = *(const ushort4*)&h[(size_t)s * D + col];
            a0 += bf2f(u.x); a1 += bf2f(u.y); a2 += bf2f(u.z); a3 += bf2f(u.w);
        }
    }
    const float di = dinv[n];
    float v0 = a0 * di, v1 = a1 * di, v2 = a2 * di, v3 = a3 * di;
    if (bias) {
        v0 += bias[col]; v1 += bias[col + 1]; v2 += bias[col + 2]; v3 += bias[col + 3];
    }
    if (RELU) {
        v0 = fmaxf(v0, 0.0f); v1 = fmaxf(v1, 0.0f);
        v2 = fmaxf(v2, 0.0f); v3 = fmaxf(v3, 0.0f);
    }
    if (wsout) {
        ushort4 o; o.x = (unsigned short)f2bf(v0); o.y = (unsigned short)f2bf(v1);
        o.z = (unsigned short)f2bf(v2); o.w = (unsigned short)f2bf(v3);
        *(ushort4*)&wsout[(size_t)n * D + col] = o;
    }
    if (wsout_sc) {
        ushort4 o; o.x = (unsigned short)f2bf(v0 * di); o.y = (unsigned short)f2bf(v1 * di);
        o.z = (unsigned short)f2bf(v2 * di); o.w = (unsigned short)f2bf(v3 * di);
        *(ushort4*)&wsout_sc[(size_t)n * D + col] = o;
    }
    if (gout) {
        const size_t gi = gbase + (size_t)n * gLD + col;
        if (flags[0]) {
            float4 o = {v0, v1, v2, v3};
            *(float4*)&((float*)gout)[gi] = o;
        } else {
            ushort4 o; o.x = (unsigned short)f2bf(v0); o.y = (unsigned short)f2bf(v1);
            o.z = (unsigned short)f2bf(v2); o.w = (unsigned short)f2bf(v3);
            *(ushort4*)&((__hip_bfloat16*)gout)[gi] = o;
        }
    }
}

// ---------------- legacy 4-layer pipeline ----------------
template <bool P>
static inline void run_layers(const void* x, const int* flags, float* Wc, float* dinv,
                              const int* base, const int* adj,
                              __hip_bfloat16* A, __hip_bfloat16* B,
                              void* d_out, hipStream_t stream) {
    gemm_mfma<128, 64, true, false, false, true, true, false><<<GEMM_GRID, 256, 0, stream>>>(
        x, 128, flags, Wc + WC_W1, 64, nullptr, dinv, A, nullptr, 0);
    agg_kernel<64, 64, true, P><<<(N_NODES + 3) / 4, 256, 0, stream>>>(
        base, adj, dinv, A, Wc + WC_B1, B, nullptr, nullptr, 0, 0, flags);
    gemm_mfma<64, 32, false, false, false, true, true, false><<<GEMM_GRID, 256, 0, stream>>>(
        B, 64, flags, Wc + WC_W2, 32, nullptr, dinv, A, nullptr, 0);
    agg_kernel<32, 32, false, P><<<(N_NODES + 7) / 8, 256, 0, stream>>>(
        base, adj, dinv, A, Wc + WC_B2, nullptr, B,
        d_out, (size_t)N_NODES * 128, 32, flags);
    agg_kernel<32, 32, false, P><<<(N_NODES + 7) / 8, 256, 0, stream>>>(
        base, adj, dinv, B, nullptr, A, nullptr, nullptr, 0, 0, flags);
    gemm_mfma<32, 64, false, true, true, true, true, false><<<GEMM_GRID, 256, 0, stream>>>(
        A, 32, flags, Wc + WC_W3, 64, Wc + WC_B3, dinv, B, nullptr, 0);
    agg_kernel<64, 64, false, P><<<(N_NODES + 3) / 4, 256, 0, stream>>>(
        base, adj, dinv, B, nullptr, A, nullptr, nullptr, 0, 0, flags);
    gemm_mfma<64, 128, false, false, true, false, false, true><<<GEMM_GRID, 256, 0, stream>>>(
        A, 64, flags, Wc + WC_W4, 128, Wc + WC_B4, dinv, nullptr, d_out, 128);
}

// ---------------- launch ----------------
extern "C" void kernel_launch(void* const* d_in, const int* in_sizes, int n_in,
                              void* d_out, int out_size, void* d_ws, size_t ws_size,
                              hipStream_t stream) {
    const void* x  = d_in[0];
    const int* ei  = (const int*)d_in[1];
    const void* W1 = d_in[2]; const void* b1 = d_in[3];
    const void* W2 = d_in[4]; const void* b2 = d_in[5];
    const void* W3 = d_in[6]; const void* b3 = d_in[7];
    const void* W4 = d_in[8]; const void* b4 = d_in[9];

    char* ws = (char*)d_ws;
    int*   flags = (int*)(ws + OFF_FLAG);
    int*   cnt   = (int*)(ws + OFF_DEG);     // padded: degree/count; legacy: deg
    float* dinv  = (float*)(ws + OFF_DINV);
    float* Wc    = (float*)(ws + OFF_WC);

    hipMemsetAsync(flags, 0, 2 * sizeof(int), stream);
    hipMemsetAsync(cnt, 0, (size_t)N_NODES * sizeof(int), stream);
    detect_kernel<<<1, 256, 0, stream>>>((const unsigned*)W1, (const unsigned*)ei, flags);
    convw_kernel<<<(WC_TOT + 255) / 256, 256, 0, stream>>>(W1, b1, W2, b2, W3, b3, W4, b4,
                                                           flags, Wc);

    if (ws_size >= NEED_PAD) {
        // ---- bucketed padded adjacency build (no per-edge global atomics) ----
        int*  pad  = (int*)(ws + OFF_PAD);
        int*  gcur = (int*)(ws + OFF_BSUM);                 // NBUK ints (legacy-only region)
        int*  ebuf = (int*)(ws + OFF_A2);                   // 8 MB, dead before gemm1
        __hip_bfloat16* A = (__hip_bfloat16*)(ws + OFF_A2); // N x 64 (also N x 32 views)
        __hip_bfloat16* B = (__hip_bfloat16*)(ws + OFF_B2); // N x 64 (also N x 32 views)
        hipMemsetAsync(gcur, 0, NBUK * sizeof(int), stream);
        bsort1_kernel<<<P1_BLK, 256, 0, stream>>>(ei, flags, gcur, ebuf);
        bsort2_kernel<<<NBUK, 1024, 0, stream>>>(gcur, ebuf, cnt, pad, dinv);

        // L1: A = (x@W1)*dinv ; B = act1 = relu(agg(A)+b1)
        gemm_mfma<128, 64, true, false, false, true, true, false><<<GEMM_GRID, 256, 0, stream>>>(
            x, 128, flags, Wc + WC_W1, 64, nullptr, dinv, A, nullptr, 0);
        aggv_kernel<64, true><<<N_NODES / 16, 256, 0, stream>>>(
            cnt, pad, dinv, A, Wc + WC_B1, B, nullptr, nullptr, 0, 0, flags);
        // L2: A = (act1@W2)*dinv ; z -> d_out, zp -> B
        gemm_mfma<64, 32, false, false, false, true, true, false><<<GEMM_GRID, 256, 0, stream>>>(
            B, 64, flags, Wc + WC_W2, 32, nullptr, dinv, A, nullptr, 0);
        aggv_kernel<32, false><<<N_NODES / 32, 256, 0, stream>>>(
            cnt, pad, dinv, A, Wc + WC_B2, nullptr, B,
            d_out, (size_t)N_NODES * 128, 32, flags);
        // L3: A = t3 = agg(zp) ; B = act3p = relu(t3@W3+b3)*dinv
        aggv_kernel<32, false><<<N_NODES / 32, 256, 0, stream>>>(
            cnt, pad, dinv, B, nullptr, A, nullptr, nullptr, 0, 0, flags);
        gemm_mfma<32, 64, false, true, true, true, true, false><<<GEMM_GRID, 256, 0, stream>>>(
            A, 32, flags, Wc + WC_W3, 64, Wc + WC_B3, dinv, B, nullptr, 0);
        // L4: A = t4 = agg(act3p) ; d_out = t4@W4 + b4
        aggv_kernel<64, false><<<N_NODES / 16, 256, 0, stream>>>(
            cnt, pad, dinv, B, nullptr, A, nullptr, nullptr, 0, 0, flags);
        gemm_mfma<64, 128, false, false, true, false, false, true><<<GEMM_GRID, 256, 0, stream>>>(
            A, 64, flags, Wc + WC_W4, 128, Wc + WC_B4, dinv, nullptr, d_out, 128);
    } else {
        // ---- legacy exact-CSR path ----
        int*   offs  = (int*)(ws + OFF_OFFS);
        int*   curs  = (int*)(ws + OFF_CURS);
        int*   bsum  = (int*)(ws + OFF_BSUM);
        int*   boff  = bsum + 128;
        int*   csr   = (int*)(ws + OFF_CSR);
        __hip_bfloat16* A = (__hip_bfloat16*)(ws + OFF_A);
        __hip_bfloat16* B = (__hip_bfloat16*)(ws + OFF_B);
        deg_kernel<<<8 * NCH, 256, 0, stream>>>(ei, flags, cnt);
        dinv_kernel<<<(N_NODES + 255) / 256, 256, 0, stream>>>(cnt, dinv);
        scan1_kernel<<<SCAN_G, SCAN_B, 0, stream>>>(cnt, bsum);
        scan2_kernel<<<1, 128, 0, stream>>>(bsum, boff);
        scan3_kernel<<<SCAN_G, SCAN_B, 0, stream>>>(cnt, boff, offs, curs);
        fill_kernel<<<8 * NCH, 256, 0, stream>>>(ei, flags, curs, csr);
        run_layers<false>(x, flags, Wc, dinv, offs, csr, A, B, d_out, stream);
    }
}